// Round 14
// baseline (345.376 us; speedup 1.0000x reference)
//
#include <hip/hip_runtime.h>

#define NPTS 8192
#define KNNK 16
#define NSLOT 17          // keep 17, fp64-refine drops the worst -> robust 16-set
#define LEAKY 0.1f

typedef short bf16x8 __attribute__((ext_vector_type(8)));
typedef float f32x4  __attribute__((ext_vector_type(4)));

// ---- knn config ----
#define KTH   1024             // threads/block (16 waves)
#define QPB   64               // queries per block -> grid 512 = 2 blocks/CU
#define CHN   32               // chunks (threads) per query
#define GQ    2                // queries per thread
#define BUFCAP 48              // survivor buffer per query
#define LCAP  3072             // active-(q,chunk) list capacity (~2.8x expected)

// ---------------------------------------------------------------------------
// R18: occupancy 2x via L2-resident candidates. R17 post-mortem: conflicts
// fell 6.9M->4.75M but time was FLAT -> conflicts off the critical path.
// Counters: VALUBusy 69%, Occupancy 33% (96KB SoA pins LDS at 159.5KB = 1
// block/CU = 4 waves/SIMD), 31% idle. Fix = R6's global-SoA idea with its
// failure cause removed: R6 died at 2 waves/SIMD; here QPB=64/grid 512 with
// 1024-thr blocks gives 2 blocks/CU = 8 waves/SIMD. knn LDS ~32KB. Swizzle
// machinery deleted (global has no bank conflicts); phase-1 loads coalesced
// (512B/quarter-wave, L1/L2-fed, ~23us total L2 traffic). GQ 4->2 (+16%
// norm cost, accepted). Threshold (64 chunk-min rank-17), compaction
// (16 lanes/entry), survivor buffer, fp64 refine: semantics identical.
// Revert criterion: VALUBusy drops => L2-latency-bound (R6 mode).
// ---------------------------------------------------------------------------

__global__ __launch_bounds__(256) void prep_kernel(
    const float* __restrict__ pc1, const float* __restrict__ pc2,
    float* __restrict__ soa)
{
    const int i = blockIdx.x * blockDim.x + threadIdx.x;   // 0..32767
    const int set = i >> 13;                               // (dir<<1)|b
    const int p   = i & (NPTS - 1);
    const int dir = set >> 1, b = set & 1;
    const float* src = (dir ? pc1 : pc2) + ((size_t)b * NPTS + p) * 3;
    float* dst = soa + (size_t)set * 3 * NPTS;
    dst[p]            = src[0];
    dst[NPTS + p]     = src[1];
    dst[2 * NPTS + p] = src[2];
}

__global__ __launch_bounds__(KTH, 8) void knn_kernel(
    const float* __restrict__ pc1, const float* __restrict__ pc2,
    const float* __restrict__ soa, int* __restrict__ knn_out)
{
    // per-query row of 96 floats: [0..47] survd, [48..95] survi (as int).
    // cols [0..63] double as the chunk-min rank table before phase 2.
    __shared__ float sbuf[QPB][2 * BUFCAP];          // 24 KB
    __shared__ float sthr[QPB];
    __shared__ int   scnt[QPB];
    __shared__ float4 qcoef[QPB];                    // 1 KB: -2*q per query
    __shared__ unsigned short list[LCAP];            // 6 KB active pairs
    __shared__ int   lcnt;

    const int t   = threadIdx.x;
    const int q0  = blockIdx.x * QPB;
    const int dir = q0 >> 14;
    const int b   = (q0 >> 13) & 1;

    const float* __restrict__ pq  = dir ? pc2 : pc1;
    const float* __restrict__ cxp = soa + (size_t)((dir << 1) | b) * 3 * NPTS;
    const float* __restrict__ cyp = cxp + NPTS;
    const float* __restrict__ czp = cxp + 2 * NPTS;
    const int n0 = q0 & (NPTS - 1);

    if (t < QPB) {
        scnt[t] = 0;
        const float* qp = pq + ((size_t)b * NPTS + n0 + t) * 3;
        qcoef[t] = make_float4(-2.0f * qp[0], -2.0f * qp[1], -2.0f * qp[2], 0.f);
    }
    if (t == 0) lcnt = 0;
    __syncthreads();

    const int ch = t & (CHN - 1);      // chunk 0..31
    const int qg = t >> 5;             // query group 0..31 (2 queries each)

    // q2 = -2*q ; |q|^2 dropped (constant per query, ordering preserved)
    float q2x[GQ], q2y[GQ], q2z[GQ];
    #pragma unroll
    for (int g = 0; g < GQ; ++g) {
        const float* qp = pq + ((size_t)b * NPTS + n0 + qg * GQ + g) * 3;
        q2x[g] = -2.0f * qp[0];
        q2y[g] = -2.0f * qp[1];
        q2z[g] = -2.0f * qp[2];
    }

    // ---- phase 1: split-range min-1 per (thread,query), L2-fed -------------
    // mA over candidates [0,4096), mB over [4096,8192): 8 cands/iter.
    float mA[GQ], mB[GQ];
    #pragma unroll
    for (int g = 0; g < GQ; ++g) { mA[g] = 3.0e38f; mB[g] = 3.0e38f; }

    #pragma unroll 2
    for (int j = 0; j < 32; ++j) {
        const int i0 = j * 128 + 4 * ch;          // first half
        const int i1 = i0 + 4096;                 // second half
        const f32x4 ax = *(const f32x4*)&cxp[i0];
        const f32x4 ay = *(const f32x4*)&cyp[i0];
        const f32x4 az = *(const f32x4*)&czp[i0];
        const f32x4 bx = *(const f32x4*)&cxp[i1];
        const f32x4 by = *(const f32x4*)&cyp[i1];
        const f32x4 bz = *(const f32x4*)&czp[i1];
        f32x4 an, bn;
        #pragma unroll
        for (int c = 0; c < 4; ++c) {
            an[c] = fmaf(ax[c], ax[c], fmaf(ay[c], ay[c], az[c] * az[c]));
            bn[c] = fmaf(bx[c], bx[c], fmaf(by[c], by[c], bz[c] * bz[c]));
        }
        #pragma unroll
        for (int g = 0; g < GQ; ++g) {
            #pragma unroll
            for (int c = 0; c < 4; ++c) {
                const float da = fmaf(q2x[g], ax[c],
                                 fmaf(q2y[g], ay[c],
                                 fmaf(q2z[g], az[c], an[c])));
                mA[g] = fminf(mA[g], da);
                const float db = fmaf(q2x[g], bx[c],
                                 fmaf(q2y[g], by[c],
                                 fmaf(q2z[g], bz[c], bn[c])));
                mB[g] = fminf(mB[g], db);
            }
        }
    }

    // ---- threshold: 17th-smallest of the 64 chunk-mins ---------------------
    // Validity: the 17 chunks with min <= tau each contribute >=1 candidate
    // <= tau => true d16 <= tau => survivors form a superset of the top-17.
    #pragma unroll
    for (int g = 0; g < GQ; ++g) {
        const int row = qg * GQ + g;
        sbuf[row][ch]      = mA[g];
        sbuf[row][32 + ch] = mB[g];
    }
    __builtin_amdgcn_wave_barrier();   // table rows are half-wave-local

    #pragma unroll
    for (int g = 0; g < GQ; ++g) {
        const int row = qg * GQ + g;
        const float vA = mA[g], vB = mB[g];
        int ltA = 0, eqA = 0, ltB = 0, eqB = 0;
        #pragma unroll
        for (int c = 0; c < 64; c += 2) {
            const float2 vp = *(const float2*)&sbuf[row][c];
            ltA += (vp.x < vA) ? 1 : 0;  eqA += (vp.x == vA) ? 1 : 0;
            ltA += (vp.y < vA) ? 1 : 0;  eqA += (vp.y == vA) ? 1 : 0;
            ltB += (vp.x < vB) ? 1 : 0;  eqB += (vp.x == vB) ? 1 : 0;
            ltB += (vp.y < vB) ? 1 : 0;  eqB += (vp.y == vB) ? 1 : 0;
        }
        // value of rank 16 (0-based): lt <= 16 < lt+eq. Ties all write
        // identical bits — benign.
        if (ltA <= 16 && ltA + eqA > 16) sthr[row] = vA;
        if (ltB <= 16 && ltB + eqB > 16) sthr[row] = vB;
    }
    __syncthreads();   // sthr now read block-wide (tasks touch any query)

    // ---- build active-(query,chunk) list (owning thread has the min) -------
    #pragma unroll
    for (int g = 0; g < GQ; ++g) {
        const int row = qg * GQ + g;
        const float tqv = sthr[row];
        if (mA[g] <= tqv) {
            const int p = atomicAdd(&lcnt, 1);
            if (p < LCAP) list[p] = (unsigned short)((row << 6) | ch);
        }
        if (mB[g] <= tqv) {
            const int p = atomicAdd(&lcnt, 1);
            if (p < LCAP) list[p] = (unsigned short)((row << 6) | 32 | ch);
        }
    }
    __syncthreads();

    // ---- phase 2 (compacted): 16 lanes/entry, 2 rows each, L2 reads --------
    {
        const int nsub = min(lcnt, LCAP) * 16;
        for (int k = t; k < nsub; k += KTH) {
            const int e  = list[k >> 4];
            const int s  = k & 15;
            const int q  = e >> 6;
            const int hf = (e >> 5) & 1;
            const int cc = e & 31;
            const float4 qc = qcoef[q];
            const float tqv = sthr[q];
            #pragma unroll
            for (int jj = 0; jj < 2; ++jj) {
                const int jl = jj * 16 + s;                    // row in half
                const int i0 = hf * 4096 + jl * 128 + 4 * cc;
                const f32x4 cx = *(const f32x4*)&cxp[i0];
                const f32x4 cy = *(const f32x4*)&cyp[i0];
                const f32x4 cz = *(const f32x4*)&czp[i0];
                #pragma unroll
                for (int c = 0; c < 4; ++c) {
                    const float cn = fmaf(cx[c], cx[c],
                                     fmaf(cy[c], cy[c], cz[c] * cz[c]));
                    const float d  = fmaf(qc.x, cx[c],
                                     fmaf(qc.y, cy[c],
                                     fmaf(qc.z, cz[c], cn)));
                    if (d <= tqv) {
                        const int pos = atomicAdd(&scnt[q], 1);
                        if (pos < BUFCAP) {
                            sbuf[q][pos] = d;
                            ((int*)&sbuf[q][BUFCAP])[pos] = i0 + c;
                        }
                    }
                }
            }
        }
    }
    __syncthreads();

    // ---- phase 3: exact top-17 of survivors + fp64 refine ------------------
    if (t < QPB) {
        const int nc = min(scnt[t], BUFCAP);

        float dist[NSLOT];   // sorted descending by (d, idx); dist[0] = worst
        int   ind[NSLOT];
        #pragma unroll
        for (int i = 0; i < NSLOT; ++i) { dist[i] = 3.0e38f; ind[i] = 0x7fffffff; }

        for (int s = 0; s < nc; ++s) {
            const float d  = sbuf[t][s];
            const int   id = ((int*)&sbuf[t][BUFCAP])[s];
            const bool better0 = (d < dist[0]) || (d == dist[0] && id < ind[0]);
            if (better0) {
                bool cprev = true;
                #pragma unroll
                for (int i = 0; i < NSLOT - 1; ++i) {
                    const bool ci = (d < dist[i + 1]) ||
                                    (d == dist[i + 1] && id < ind[i + 1]);
                    const float nv = ci ? dist[i + 1] : (cprev ? d  : dist[i]);
                    const int   ni = ci ? ind[i + 1]  : (cprev ? id : ind[i]);
                    dist[i] = nv; ind[i] = ni;
                    cprev = ci;
                }
                if (cprev) { dist[NSLOT - 1] = d; ind[NSLOT - 1] = id; }
            }
        }

        const float* qpp = pq + ((size_t)b * NPTS + n0 + t) * 3;
        const double dqx = (double)qpp[0], dqy = (double)qpp[1], dqz = (double)qpp[2];
        double dd[NSLOT];
        #pragma unroll
        for (int i = 0; i < NSLOT; ++i) {
            const int id = ind[i];
            const double dx = (double)cxp[id] - dqx;
            const double dy = (double)cyp[id] - dqy;
            const double dz = (double)czp[id] - dqz;
            dd[i] = dx * dx + dy * dy + dz * dz;
        }
        int worst = 0; double wd = dd[0];
        #pragma unroll
        for (int i = 1; i < NSLOT; ++i) { if (dd[i] > wd) { wd = dd[i]; worst = i; } }

        int* outp = knn_out + (size_t)(q0 + t) * KNNK;
        int slot = 0;
        #pragma unroll
        for (int i = 0; i < NSLOT; ++i) {
            if (i != worst) outp[slot++] = ind[i];
        }
    }
}

// ---------------------------------------------------------------------------
// Kernel 2 (R10, unchanged): feature MLP, 16 points/block in 4 pipelined
// groups of 4 with register-staged gather overlap.
// ---------------------------------------------------------------------------
#define PTS 16     // points per block
#define NG  4      // groups of 4 points

__device__ __forceinline__ unsigned int packhl(float f) {
    const unsigned int u = __float_as_uint(f);
    const unsigned int h = u & 0xffff0000u;
    const float lf = f - __uint_as_float(h);
    return h | (__float_as_uint(lf) >> 16);
}

__device__ __forceinline__ void build_b(const float* __restrict__ wrow,
                                        bf16x8* hi, bf16x8* lo) {
    union { unsigned int u[4]; bf16x8 v; } H, L;
    #pragma unroll
    for (int r = 0; r < 4; ++r) {
        const float f0 = wrow[2 * r], f1 = wrow[2 * r + 1];
        const unsigned int h0 = __float_as_uint(f0) & 0xffff0000u;
        const unsigned int h1 = __float_as_uint(f1) & 0xffff0000u;
        const float l0 = f0 - __uint_as_float(h0);
        const float l1 = f1 - __uint_as_float(h1);
        H.u[r] = h1 | (h0 >> 16);
        L.u[r] = (__float_as_uint(l1) & 0xffff0000u) | (__float_as_uint(l0) >> 16);
    }
    *hi = H.v; *lo = L.v;
}

__device__ __forceinline__ void unpack_a(const unsigned int* __restrict__ Tu,
                                         bf16x8* hi, bf16x8* lo) {
    union { unsigned int u[4]; bf16x8 v; } H, L;
    #pragma unroll
    for (int r = 0; r < 4; ++r) {
        const unsigned int a = Tu[2 * r + 1], bb = Tu[2 * r];
        H.u[r] = __builtin_amdgcn_perm(a, bb, 0x07060302u);  // [a.hi16 : b.hi16]
        L.u[r] = __builtin_amdgcn_perm(a, bb, 0x05040100u);  // [a.lo16 : b.lo16]
    }
    *hi = H.v; *lo = L.v;
}

__device__ __forceinline__ f32x4 mfma3(f32x4 acc, bf16x8 ah, bf16x8 al,
                                       bf16x8 bh, bf16x8 bl) {
    acc = __builtin_amdgcn_mfma_f32_16x16x32_bf16(ah, bl, acc, 0, 0, 0);
    acc = __builtin_amdgcn_mfma_f32_16x16x32_bf16(al, bh, acc, 0, 0, 0);
    acc = __builtin_amdgcn_mfma_f32_16x16x32_bf16(ah, bh, acc, 0, 0, 0);
    return acc;
}

__global__ __launch_bounds__(256, 4) void feat_kernel(
    const float* __restrict__ pc1, const float* __restrict__ pc2,
    const float* __restrict__ feat1, const float* __restrict__ feat2,
    const float* __restrict__ pos_w, const float* __restrict__ pos_b,
    const float* __restrict__ w0, const float* __restrict__ b0,
    const float* __restrict__ w1, const float* __restrict__ b1,
    const float* __restrict__ t1w, const float* __restrict__ t1b,
    const float* __restrict__ t2w, const float* __restrict__ t2b,
    const int* __restrict__ knn, float* __restrict__ out)
{
    __shared__ unsigned int T0[4][16][68];    // 17.4 KB packed activations
    __shared__ unsigned int T1[4][16][68];    // 17.4 KB
    __shared__ float sm[PTS][64];             // 4 KB pooled features (16 pts)

    const int t    = threadIdx.x;
    const int w    = t >> 6;          // wave = N-tile index 0..3
    const int lane = t & 63;
    const int m    = lane & 15;       // A-row (neighbor) / C-col (channel)
    const int quad = lane >> 4;

    const int p0  = blockIdx.x * PTS;
    const int dir = p0 >> 14, bt = (p0 >> 13) & 1;
    const int n0  = p0 & (NPTS - 1);

    const float* __restrict__ pqd = dir ? pc2 : pc1;
    const float* __restrict__ pcd = dir ? pc1 : pc2;
    const float* __restrict__ fqd = dir ? feat2 : feat1;
    const float* __restrict__ fcd = dir ? feat1 : feat2;

    // ---- per-block setup (amortized over 16 points) ------------------------
    const int ocol = w * 16 + m;               // this lane's output channel
    bf16x8 Bh[2][2], Bl[2][2];                 // [layer][ktile]
    #pragma unroll
    for (int kt = 0; kt < 2; ++kt) {
        build_b(&w0[(size_t)ocol * 64 + kt * 32 + quad * 8], &Bh[0][kt], &Bl[0][kt]);
        build_b(&w1[(size_t)ocol * 64 + kt * 32 + quad * 8], &Bh[1][kt], &Bl[1][kt]);
    }
    const float bias1 = b0[ocol];
    const float bias2 = b1[ocol];

    const int cg0 = w * 16 + quad * 4;
    float pbc[4], pwx[4], pwy[4], pwz[4];
    #pragma unroll
    for (int i = 0; i < 4; ++i) {
        pbc[i] = pos_b[cg0 + i];
        pwx[i] = pos_w[(cg0 + i) * 3 + 0];
        pwy[i] = pos_w[(cg0 + i) * 3 + 1];
        pwz[i] = pos_w[(cg0 + i) * 3 + 2];
    }

    // ---- register staging for the pipelined gather -------------------------
    float  sdx[4], sdy[4], sdz[4];
    float4 sgf[4], sfq[4];

    auto loadg = [&](int gg) {      // issue group gg's gathers into registers
        #pragma unroll
        for (int pt = 0; pt < 4; ++pt) {
            const int pp = p0 + gg * 4 + pt;
            const int nn = n0 + gg * 4 + pt;
            const int id = knn[(size_t)pp * KNNK + m];
            const float* qp  = pqd + ((size_t)bt * NPTS + nn) * 3;
            const float* nbp = pcd + ((size_t)bt * NPTS + id) * 3;
            sdx[pt] = nbp[0] - qp[0];
            sdy[pt] = nbp[1] - qp[1];
            sdz[pt] = nbp[2] - qp[2];
            sgf[pt] = *(const float4*)&fcd[((size_t)bt * NPTS + id) * 64 + cg0];
            sfq[pt] = *(const float4*)&fqd[((size_t)bt * NPTS + nn) * 64 + cg0];
        }
    };

    auto storeg = [&]() {           // initial layer from staged regs -> T0
        #pragma unroll
        for (int pt = 0; pt < 4; ++pt) {
            const float gfa[4] = {sgf[pt].x, sgf[pt].y, sgf[pt].z, sgf[pt].w};
            const float fqa[4] = {sfq[pt].x, sfq[pt].y, sfq[pt].z, sfq[pt].w};
            uint4 U;
            unsigned int* Up = (unsigned int*)&U;
            #pragma unroll
            for (int i = 0; i < 4; ++i) {
                float v = gfa[i] + fqa[i] + pbc[i];
                v = fmaf(sdx[pt], pwx[i], v);
                v = fmaf(sdy[pt], pwy[i], v);
                v = fmaf(sdz[pt], pwz[i], v);
                v = fmaxf(v, LEAKY * v);
                Up[i] = packhl(v);
            }
            *(uint4*)&T0[pt][m][cg0] = U;
        }
    };

    // ---- prologue: group 0 -------------------------------------------------
    loadg(0);
    storeg();
    __syncthreads();

    // ---- pipelined group loop ----------------------------------------------
    #pragma unroll
    for (int g = 0; g < NG; ++g) {
        if (g + 1 < NG) loadg(g + 1);   // gathers hide under B(g)+C(g)

        // ---- stage B: layer 1 (MFMA) T0 -> T1 ------------------------------
        #pragma unroll
        for (int pt = 0; pt < 4; ++pt) {
            unsigned int Tu[8];
            bf16x8 Ah, Al;
            f32x4 acc = {0.f, 0.f, 0.f, 0.f};
            #pragma unroll
            for (int kt = 0; kt < 2; ++kt) {
                *(uint4*)&Tu[0] = *(const uint4*)&T0[pt][m][kt * 32 + quad * 8];
                *(uint4*)&Tu[4] = *(const uint4*)&T0[pt][m][kt * 32 + quad * 8 + 4];
                unpack_a(Tu, &Ah, &Al);
                acc = mfma3(acc, Ah, Al, Bh[0][kt], Bl[0][kt]);
            }
            #pragma unroll
            for (int r = 0; r < 4; ++r) {
                float v = acc[r] + bias1;
                v = fmaxf(v, LEAKY * v);
                T1[pt][quad * 4 + r][ocol] = packhl(v);
            }
        }
        __syncthreads();   // all waves done reading T0(g), T1(g) visible

        if (g + 1 < NG) storeg();       // overwrite T0 with group g+1

        // ---- stage C: layer 2 (MFMA) + max-pool -> sm ----------------------
        #pragma unroll
        for (int pt = 0; pt < 4; ++pt) {
            unsigned int Tu[8];
            bf16x8 Ah, Al;
            f32x4 acc = {0.f, 0.f, 0.f, 0.f};
            #pragma unroll
            for (int kt = 0; kt < 2; ++kt) {
                *(uint4*)&Tu[0] = *(const uint4*)&T1[pt][m][kt * 32 + quad * 8];
                *(uint4*)&Tu[4] = *(const uint4*)&T1[pt][m][kt * 32 + quad * 8 + 4];
                unpack_a(Tu, &Ah, &Al);
                acc = mfma3(acc, Ah, Al, Bh[1][kt], Bl[1][kt]);
            }
            float mx = -3.0e38f;
            #pragma unroll
            for (int r = 0; r < 4; ++r) {
                float v = acc[r] + bias2;
                v = fmaxf(v, LEAKY * v);
                mx = fmaxf(mx, v);
            }
            mx = fmaxf(mx, __shfl_xor(mx, 16));
            mx = fmaxf(mx, __shfl_xor(mx, 32));
            if (quad == 0) sm[g * 4 + pt][ocol] = mx;
        }
        __syncthreads();   // T0(g+1) ready for B(g+1); sm(g) visible
    }

    // ---- stage D: final 64->128 linear, 16 points, weights loaded once -----
    {
        const float* __restrict__ tw = dir ? t2w : t1w;
        const float* __restrict__ tb = dir ? t2b : t1b;
        const int o  = t & 127;
        const int pg = t >> 7;                 // 0..1: which pairs this thread owns
        float acc[8];
        const float bz = tb[o];
        #pragma unroll
        for (int i = 0; i < 8; ++i) acc[i] = bz;
        #pragma unroll
        for (int cc = 0; cc < 64; cc += 4) {
            const float4 wq = *(const float4*)&tw[(size_t)o * 64 + cc];
            #pragma unroll
            for (int pr = 0; pr < 4; ++pr) {
                const int pa = (2 * pr + pg) * 2;       // pair -> even point
                const float4 a0 = *(const float4*)&sm[pa][cc];
                const float4 a1 = *(const float4*)&sm[pa + 1][cc];
                float x0 = acc[2 * pr], x1 = acc[2 * pr + 1];
                x0 = fmaf(a0.x, wq.x, x0); x0 = fmaf(a0.y, wq.y, x0);
                x0 = fmaf(a0.z, wq.z, x0); x0 = fmaf(a0.w, wq.w, x0);
                x1 = fmaf(a1.x, wq.x, x1); x1 = fmaf(a1.y, wq.y, x1);
                x1 = fmaf(a1.z, wq.z, x1); x1 = fmaf(a1.w, wq.w, x1);
                acc[2 * pr] = x0; acc[2 * pr + 1] = x1;
            }
        }
        float* op = out + (size_t)dir * (2 * NPTS * 128);
        #pragma unroll
        for (int pr = 0; pr < 4; ++pr) {
            const int pa = (2 * pr + pg) * 2;
            op[((size_t)bt * NPTS + n0 + pa) * 128 + o]     = acc[2 * pr];
            op[((size_t)bt * NPTS + n0 + pa + 1) * 128 + o] = acc[2 * pr + 1];
        }
    }
}

// ---------------------------------------------------------------------------
extern "C" void kernel_launch(void* const* d_in, const int* in_sizes, int n_in,
                              void* d_out, int out_size, void* d_ws, size_t ws_size,
                              hipStream_t stream)
{
    const float* pc1   = (const float*)d_in[0];
    const float* pc2   = (const float*)d_in[1];
    const float* feat1 = (const float*)d_in[2];
    const float* feat2 = (const float*)d_in[3];
    const float* pos_w = (const float*)d_in[4];
    const float* pos_b = (const float*)d_in[5];
    const float* w0    = (const float*)d_in[6];
    const float* b0    = (const float*)d_in[7];
    const float* w1    = (const float*)d_in[8];
    const float* b1    = (const float*)d_in[9];
    const float* t1w   = (const float*)d_in[10];
    const float* t1b   = (const float*)d_in[11];
    const float* t2w   = (const float*)d_in[12];
    const float* t2b   = (const float*)d_in[13];

    int*   knn = (int*)d_ws;          // 32768 * 16 ints = 2 MB scratch
    float* out = (float*)d_out;

    // candidate SoA scratch: 4 sets x 3 coords x 8192 = 384 KB.
    // Prefer workspace tail; fall back to d_out (fully overwritten later by
    // feat_kernel, stream-ordered, so this is hazard-free).
    const size_t knn_bytes = (size_t)32768 * KNNK * sizeof(int);
    const size_t soa_bytes = (size_t)4 * 3 * NPTS * sizeof(float);
    float* soa;
    if (ws_size >= knn_bytes + soa_bytes)
        soa = (float*)((char*)d_ws + knn_bytes);
    else
        soa = (float*)d_out;

    hipLaunchKernelGGL(prep_kernel, dim3(32768 / 256), dim3(256), 0, stream,
                       pc1, pc2, soa);
    hipLaunchKernelGGL(knn_kernel, dim3(32768 / QPB), dim3(KTH), 0, stream,
                       pc1, pc2, soa, knn);
    hipLaunchKernelGGL(feat_kernel, dim3(32768 / PTS), dim3(256), 0, stream,
                       pc1, pc2, feat1, feat2, pos_w, pos_b,
                       w0, b0, w1, b1, t1w, t1b, t2w, t2b, knn, out);
}

// Round 15
// 249.330 us; speedup vs baseline: 1.3852x; 1.3852x over previous
//
#include <hip/hip_runtime.h>

#define NPTS 8192
#define KNNK 16
#define NSLOT 17          // keep 17, fp64-refine drops the worst -> robust 16-set
#define LEAKY 0.1f

typedef short bf16x8 __attribute__((ext_vector_type(8)));
typedef float f32x4  __attribute__((ext_vector_type(4)));

// ---- knn config ----
#define KTH   1024             // threads/block (16 waves): 16 waves/CU, 1 blk/CU
#define QPB   128              // queries per block -> grid 256
#define CHN   32               // chunks (threads) per query
#define GQ    4                // queries per thread
#define BUFCAP 48              // survivor buffer per query
#define LCAP  6144             // active-(q,chunk) list capacity (~2.8x expected)

// ---------------------------------------------------------------------------
// R19 == R16 reverted-to (best known: 249.5us total, knn 103.1us).
// R18 post-mortem: L2-resident candidates met the pre-registered revert
// criterion — VALUBusy 69->38%, knn 103.6->204us, hbm_bytes 3.9->58MB/disp
// (cross-XCD L2 thrash; bandwidth-bound, not just latency). Lesson banked:
// the 537M-pair candidate stream must be LDS-fed; 33% occupancy is the
// price, VALU ~70% busy is the binding pipe. R17's extra conflict polish
// was flat (conflicts off critical path). This is the R16 structure:
// rotated-swizzle LDS SoA + min-1 split-range chunk-min threshold +
// compacted phase 2 (8-lane entries) + exact fp32 d' survivors +
// top-17 + fp64 refine.
// ---------------------------------------------------------------------------
__device__ __forceinline__ int swz(int i) {
    const int j = i >> 7;
    return (i & ~127) | ((((i >> 2) + j) & 31) << 2) | (i & 3);
}

__global__ __launch_bounds__(KTH, 4) void knn_kernel(
    const float* __restrict__ pc1, const float* __restrict__ pc2,
    int* __restrict__ knn_out)
{
    __shared__ float sx[NPTS], sy[NPTS], sz[NPTS];   // 96 KB swizzled SoA
    // per-query row of 96 floats: [0..47] survd, [48..95] survi (as int).
    // cols [0..63] double as the chunk-min rank table before phase 2.
    __shared__ float sbuf[QPB][2 * BUFCAP];          // 48 KB
    __shared__ float sthr[QPB];
    __shared__ int   scnt[QPB];
    __shared__ float4 qcoef[QPB];                    // 2 KB: -2*q per query
    __shared__ unsigned short list[LCAP];            // 12 KB active pairs
    __shared__ int   lcnt;

    const int t   = threadIdx.x;
    const int q0  = blockIdx.x * QPB;
    const int dir = q0 >> 14;
    const int b   = (q0 >> 13) & 1;

    const float* __restrict__ pq    = dir ? pc2 : pc1;
    const float* __restrict__ pcand = dir ? pc1 : pc2;
    const int n0 = q0 & (NPTS - 1);

    const float* src = pcand + (size_t)b * NPTS * 3;
    for (int i = t; i < NPTS; i += KTH) {
        const int p = swz(i);
        sx[p] = src[3 * i];
        sy[p] = src[3 * i + 1];
        sz[p] = src[3 * i + 2];
    }
    if (t < QPB) {
        scnt[t] = 0;
        const float* qp = pq + ((size_t)b * NPTS + n0 + t) * 3;
        qcoef[t] = make_float4(-2.0f * qp[0], -2.0f * qp[1], -2.0f * qp[2], 0.f);
    }
    if (t == 0) lcnt = 0;
    __syncthreads();

    const int ch = t & (CHN - 1);      // chunk 0..31
    const int qg = t >> 5;             // query group 0..31 (4 queries each)

    // q2 = -2*q ; |q|^2 dropped (constant per query, ordering preserved)
    float q2x[GQ], q2y[GQ], q2z[GQ];
    #pragma unroll
    for (int g = 0; g < GQ; ++g) {
        const float* qp = pq + ((size_t)b * NPTS + n0 + qg * GQ + g) * 3;
        q2x[g] = -2.0f * qp[0];
        q2y[g] = -2.0f * qp[1];
        q2z[g] = -2.0f * qp[2];
    }

    // ---- phase 1: split-range min-1 per (thread,query) ---------------------
    // mA over rows [0,32) (cands [0,4096)), mB over rows [32,64).
    float mA[GQ], mB[GQ];
    #pragma unroll
    for (int g = 0; g < GQ; ++g) { mA[g] = 3.0e38f; mB[g] = 3.0e38f; }

    #pragma unroll 2
    for (int j = 0; j < 32; ++j) {
        const int rot = ((ch + j) & 31) * 4;     // swizzled slot offset
        const int pA  = j * 128 + rot;
        const int pB  = (j + 32) * 128 + rot;    // (j+32)%32==j -> same rot
        const f32x4 ax = *(const f32x4*)&sx[pA];
        const f32x4 ay = *(const f32x4*)&sy[pA];
        const f32x4 az = *(const f32x4*)&sz[pA];
        const f32x4 bx = *(const f32x4*)&sx[pB];
        const f32x4 by = *(const f32x4*)&sy[pB];
        const f32x4 bz = *(const f32x4*)&sz[pB];
        f32x4 an, bn;
        #pragma unroll
        for (int c = 0; c < 4; ++c) {
            an[c] = fmaf(ax[c], ax[c], fmaf(ay[c], ay[c], az[c] * az[c]));
            bn[c] = fmaf(bx[c], bx[c], fmaf(by[c], by[c], bz[c] * bz[c]));
        }
        #pragma unroll
        for (int g = 0; g < GQ; ++g) {
            #pragma unroll
            for (int c = 0; c < 4; ++c) {
                const float da = fmaf(q2x[g], ax[c],
                                 fmaf(q2y[g], ay[c],
                                 fmaf(q2z[g], az[c], an[c])));
                mA[g] = fminf(mA[g], da);
                const float db = fmaf(q2x[g], bx[c],
                                 fmaf(q2y[g], by[c],
                                 fmaf(q2z[g], bz[c], bn[c])));
                mB[g] = fminf(mB[g], db);
            }
        }
    }

    // ---- threshold: 17th-smallest of the 64 chunk-mins ---------------------
    // Validity: the 17 chunks with min <= tau each contribute >=1 candidate
    // <= tau => true d16 <= tau => survivors form a superset of the top-17.
    #pragma unroll
    for (int g = 0; g < GQ; ++g) {
        const int row = qg * GQ + g;
        sbuf[row][ch]      = mA[g];
        sbuf[row][32 + ch] = mB[g];
    }
    __builtin_amdgcn_wave_barrier();   // table rows are half-wave-local

    #pragma unroll
    for (int g = 0; g < GQ; ++g) {
        const int row = qg * GQ + g;
        const float vA = mA[g], vB = mB[g];
        int ltA = 0, eqA = 0, ltB = 0, eqB = 0;
        #pragma unroll
        for (int c = 0; c < 64; c += 2) {
            const float2 vp = *(const float2*)&sbuf[row][c];
            ltA += (vp.x < vA) ? 1 : 0;  eqA += (vp.x == vA) ? 1 : 0;
            ltA += (vp.y < vA) ? 1 : 0;  eqA += (vp.y == vA) ? 1 : 0;
            ltB += (vp.x < vB) ? 1 : 0;  eqB += (vp.x == vB) ? 1 : 0;
            ltB += (vp.y < vB) ? 1 : 0;  eqB += (vp.y == vB) ? 1 : 0;
        }
        // value of rank 16 (0-based): lt <= 16 < lt+eq. Ties all write
        // identical bits — benign.
        if (ltA <= 16 && ltA + eqA > 16) sthr[row] = vA;
        if (ltB <= 16 && ltB + eqB > 16) sthr[row] = vB;
    }
    __syncthreads();   // sthr now read block-wide (tasks touch any query)

    // ---- build active-(query,chunk) list (owning thread has the min) -------
    #pragma unroll
    for (int g = 0; g < GQ; ++g) {
        const int row = qg * GQ + g;
        const float tqv = sthr[row];
        if (mA[g] <= tqv) {
            const int p = atomicAdd(&lcnt, 1);
            if (p < LCAP) list[p] = (unsigned short)((row << 6) | ch);
        }
        if (mB[g] <= tqv) {
            const int p = atomicAdd(&lcnt, 1);
            if (p < LCAP) list[p] = (unsigned short)((row << 6) | 32 | ch);
        }
    }
    __syncthreads();

    // ---- phase 2 (compacted): 8 subtasks/entry, rows jj*8+s ----------------
    // Lane s of a task group reads rows j..j+7 -> swizzled slots
    // (cc+j)..(cc+j+7): 8 consecutive slots = 32 banks once within group.
    {
        const int nsub = min(lcnt, LCAP) * 8;
        for (int k = t; k < nsub; k += KTH) {
            const int e  = list[k >> 3];
            const int s  = k & 7;
            const int q  = e >> 6;
            const int hf = (e >> 5) & 1;
            const int cc = e & 31;
            const float4 qc = qcoef[q];
            const float tqv = sthr[q];
            #pragma unroll
            for (int jj = 0; jj < 4; ++jj) {
                const int jl   = jj * 8 + s;                   // row in half
                const int lg0  = hf * 4096 + jl * 128 + 4 * cc; // logical idx
                const int ph0  = hf * 4096 + jl * 128 + (((cc + jl) & 31) * 4);
                const f32x4 cx = *(const f32x4*)&sx[ph0];
                const f32x4 cy = *(const f32x4*)&sy[ph0];
                const f32x4 cz = *(const f32x4*)&sz[ph0];
                #pragma unroll
                for (int c = 0; c < 4; ++c) {
                    const float cn = fmaf(cx[c], cx[c],
                                     fmaf(cy[c], cy[c], cz[c] * cz[c]));
                    const float d  = fmaf(qc.x, cx[c],
                                     fmaf(qc.y, cy[c],
                                     fmaf(qc.z, cz[c], cn)));
                    if (d <= tqv) {
                        const int pos = atomicAdd(&scnt[q], 1);
                        if (pos < BUFCAP) {
                            sbuf[q][pos] = d;
                            ((int*)&sbuf[q][BUFCAP])[pos] = lg0 + c;
                        }
                    }
                }
            }
        }
    }
    __syncthreads();

    // ---- phase 3: exact top-17 of survivors + fp64 refine ------------------
    if (t < QPB) {
        const int nc = min(scnt[t], BUFCAP);

        float dist[NSLOT];   // sorted descending by (d, idx); dist[0] = worst
        int   ind[NSLOT];
        #pragma unroll
        for (int i = 0; i < NSLOT; ++i) { dist[i] = 3.0e38f; ind[i] = 0x7fffffff; }

        for (int s = 0; s < nc; ++s) {
            const float d  = sbuf[t][s];
            const int   id = ((int*)&sbuf[t][BUFCAP])[s];
            const bool better0 = (d < dist[0]) || (d == dist[0] && id < ind[0]);
            if (better0) {
                bool cprev = true;
                #pragma unroll
                for (int i = 0; i < NSLOT - 1; ++i) {
                    const bool ci = (d < dist[i + 1]) ||
                                    (d == dist[i + 1] && id < ind[i + 1]);
                    const float nv = ci ? dist[i + 1] : (cprev ? d  : dist[i]);
                    const int   ni = ci ? ind[i + 1]  : (cprev ? id : ind[i]);
                    dist[i] = nv; ind[i] = ni;
                    cprev = ci;
                }
                if (cprev) { dist[NSLOT - 1] = d; ind[NSLOT - 1] = id; }
            }
        }

        const float* qpp = pq + ((size_t)b * NPTS + n0 + t) * 3;
        const double dqx = (double)qpp[0], dqy = (double)qpp[1], dqz = (double)qpp[2];
        double dd[NSLOT];
        #pragma unroll
        for (int i = 0; i < NSLOT; ++i) {
            const int p = swz(ind[i]);
            const double dx = (double)sx[p] - dqx;
            const double dy = (double)sy[p] - dqy;
            const double dz = (double)sz[p] - dqz;
            dd[i] = dx * dx + dy * dy + dz * dz;
        }
        int worst = 0; double wd = dd[0];
        #pragma unroll
        for (int i = 1; i < NSLOT; ++i) { if (dd[i] > wd) { wd = dd[i]; worst = i; } }

        int* outp = knn_out + (size_t)(q0 + t) * KNNK;
        int slot = 0;
        #pragma unroll
        for (int i = 0; i < NSLOT; ++i) {
            if (i != worst) outp[slot++] = ind[i];
        }
    }
}

// ---------------------------------------------------------------------------
// Kernel 2 (R10, unchanged): feature MLP, 16 points/block in 4 pipelined
// groups of 4 with register-staged gather overlap.
// ---------------------------------------------------------------------------
#define PTS 16     // points per block
#define NG  4      // groups of 4 points

__device__ __forceinline__ unsigned int packhl(float f) {
    const unsigned int u = __float_as_uint(f);
    const unsigned int h = u & 0xffff0000u;
    const float lf = f - __uint_as_float(h);
    return h | (__float_as_uint(lf) >> 16);
}

__device__ __forceinline__ void build_b(const float* __restrict__ wrow,
                                        bf16x8* hi, bf16x8* lo) {
    union { unsigned int u[4]; bf16x8 v; } H, L;
    #pragma unroll
    for (int r = 0; r < 4; ++r) {
        const float f0 = wrow[2 * r], f1 = wrow[2 * r + 1];
        const unsigned int h0 = __float_as_uint(f0) & 0xffff0000u;
        const unsigned int h1 = __float_as_uint(f1) & 0xffff0000u;
        const float l0 = f0 - __uint_as_float(h0);
        const float l1 = f1 - __uint_as_float(h1);
        H.u[r] = h1 | (h0 >> 16);
        L.u[r] = (__float_as_uint(l1) & 0xffff0000u) | (__float_as_uint(l0) >> 16);
    }
    *hi = H.v; *lo = L.v;
}

__device__ __forceinline__ void unpack_a(const unsigned int* __restrict__ Tu,
                                         bf16x8* hi, bf16x8* lo) {
    union { unsigned int u[4]; bf16x8 v; } H, L;
    #pragma unroll
    for (int r = 0; r < 4; ++r) {
        const unsigned int a = Tu[2 * r + 1], bb = Tu[2 * r];
        H.u[r] = __builtin_amdgcn_perm(a, bb, 0x07060302u);  // [a.hi16 : b.hi16]
        L.u[r] = __builtin_amdgcn_perm(a, bb, 0x05040100u);  // [a.lo16 : b.lo16]
    }
    *hi = H.v; *lo = L.v;
}

__device__ __forceinline__ f32x4 mfma3(f32x4 acc, bf16x8 ah, bf16x8 al,
                                       bf16x8 bh, bf16x8 bl) {
    acc = __builtin_amdgcn_mfma_f32_16x16x32_bf16(ah, bl, acc, 0, 0, 0);
    acc = __builtin_amdgcn_mfma_f32_16x16x32_bf16(al, bh, acc, 0, 0, 0);
    acc = __builtin_amdgcn_mfma_f32_16x16x32_bf16(ah, bh, acc, 0, 0, 0);
    return acc;
}

__global__ __launch_bounds__(256, 4) void feat_kernel(
    const float* __restrict__ pc1, const float* __restrict__ pc2,
    const float* __restrict__ feat1, const float* __restrict__ feat2,
    const float* __restrict__ pos_w, const float* __restrict__ pos_b,
    const float* __restrict__ w0, const float* __restrict__ b0,
    const float* __restrict__ w1, const float* __restrict__ b1,
    const float* __restrict__ t1w, const float* __restrict__ t1b,
    const float* __restrict__ t2w, const float* __restrict__ t2b,
    const int* __restrict__ knn, float* __restrict__ out)
{
    __shared__ unsigned int T0[4][16][68];    // 17.4 KB packed activations
    __shared__ unsigned int T1[4][16][68];    // 17.4 KB
    __shared__ float sm[PTS][64];             // 4 KB pooled features (16 pts)

    const int t    = threadIdx.x;
    const int w    = t >> 6;          // wave = N-tile index 0..3
    const int lane = t & 63;
    const int m    = lane & 15;       // A-row (neighbor) / C-col (channel)
    const int quad = lane >> 4;

    const int p0  = blockIdx.x * PTS;
    const int dir = p0 >> 14, bt = (p0 >> 13) & 1;
    const int n0  = p0 & (NPTS - 1);

    const float* __restrict__ pqd = dir ? pc2 : pc1;
    const float* __restrict__ pcd = dir ? pc1 : pc2;
    const float* __restrict__ fqd = dir ? feat2 : feat1;
    const float* __restrict__ fcd = dir ? feat1 : feat2;

    // ---- per-block setup (amortized over 16 points) ------------------------
    const int ocol = w * 16 + m;               // this lane's output channel
    bf16x8 Bh[2][2], Bl[2][2];                 // [layer][ktile]
    #pragma unroll
    for (int kt = 0; kt < 2; ++kt) {
        build_b(&w0[(size_t)ocol * 64 + kt * 32 + quad * 8], &Bh[0][kt], &Bl[0][kt]);
        build_b(&w1[(size_t)ocol * 64 + kt * 32 + quad * 8], &Bh[1][kt], &Bl[1][kt]);
    }
    const float bias1 = b0[ocol];
    const float bias2 = b1[ocol];

    const int cg0 = w * 16 + quad * 4;
    float pbc[4], pwx[4], pwy[4], pwz[4];
    #pragma unroll
    for (int i = 0; i < 4; ++i) {
        pbc[i] = pos_b[cg0 + i];
        pwx[i] = pos_w[(cg0 + i) * 3 + 0];
        pwy[i] = pos_w[(cg0 + i) * 3 + 1];
        pwz[i] = pos_w[(cg0 + i) * 3 + 2];
    }

    // ---- register staging for the pipelined gather -------------------------
    float  sdx[4], sdy[4], sdz[4];
    float4 sgf[4], sfq[4];

    auto loadg = [&](int gg) {      // issue group gg's gathers into registers
        #pragma unroll
        for (int pt = 0; pt < 4; ++pt) {
            const int pp = p0 + gg * 4 + pt;
            const int nn = n0 + gg * 4 + pt;
            const int id = knn[(size_t)pp * KNNK + m];
            const float* qp  = pqd + ((size_t)bt * NPTS + nn) * 3;
            const float* nbp = pcd + ((size_t)bt * NPTS + id) * 3;
            sdx[pt] = nbp[0] - qp[0];
            sdy[pt] = nbp[1] - qp[1];
            sdz[pt] = nbp[2] - qp[2];
            sgf[pt] = *(const float4*)&fcd[((size_t)bt * NPTS + id) * 64 + cg0];
            sfq[pt] = *(const float4*)&fqd[((size_t)bt * NPTS + nn) * 64 + cg0];
        }
    };

    auto storeg = [&]() {           // initial layer from staged regs -> T0
        #pragma unroll
        for (int pt = 0; pt < 4; ++pt) {
            const float gfa[4] = {sgf[pt].x, sgf[pt].y, sgf[pt].z, sgf[pt].w};
            const float fqa[4] = {sfq[pt].x, sfq[pt].y, sfq[pt].z, sfq[pt].w};
            uint4 U;
            unsigned int* Up = (unsigned int*)&U;
            #pragma unroll
            for (int i = 0; i < 4; ++i) {
                float v = gfa[i] + fqa[i] + pbc[i];
                v = fmaf(sdx[pt], pwx[i], v);
                v = fmaf(sdy[pt], pwy[i], v);
                v = fmaf(sdz[pt], pwz[i], v);
                v = fmaxf(v, LEAKY * v);
                Up[i] = packhl(v);
            }
            *(uint4*)&T0[pt][m][cg0] = U;
        }
    };

    // ---- prologue: group 0 -------------------------------------------------
    loadg(0);
    storeg();
    __syncthreads();

    // ---- pipelined group loop ----------------------------------------------
    #pragma unroll
    for (int g = 0; g < NG; ++g) {
        if (g + 1 < NG) loadg(g + 1);   // gathers hide under B(g)+C(g)

        // ---- stage B: layer 1 (MFMA) T0 -> T1 ------------------------------
        #pragma unroll
        for (int pt = 0; pt < 4; ++pt) {
            unsigned int Tu[8];
            bf16x8 Ah, Al;
            f32x4 acc = {0.f, 0.f, 0.f, 0.f};
            #pragma unroll
            for (int kt = 0; kt < 2; ++kt) {
                *(uint4*)&Tu[0] = *(const uint4*)&T0[pt][m][kt * 32 + quad * 8];
                *(uint4*)&Tu[4] = *(const uint4*)&T0[pt][m][kt * 32 + quad * 8 + 4];
                unpack_a(Tu, &Ah, &Al);
                acc = mfma3(acc, Ah, Al, Bh[0][kt], Bl[0][kt]);
            }
            #pragma unroll
            for (int r = 0; r < 4; ++r) {
                float v = acc[r] + bias1;
                v = fmaxf(v, LEAKY * v);
                T1[pt][quad * 4 + r][ocol] = packhl(v);
            }
        }
        __syncthreads();   // all waves done reading T0(g), T1(g) visible

        if (g + 1 < NG) storeg();       // overwrite T0 with group g+1

        // ---- stage C: layer 2 (MFMA) + max-pool -> sm ----------------------
        #pragma unroll
        for (int pt = 0; pt < 4; ++pt) {
            unsigned int Tu[8];
            bf16x8 Ah, Al;
            f32x4 acc = {0.f, 0.f, 0.f, 0.f};
            #pragma unroll
            for (int kt = 0; kt < 2; ++kt) {
                *(uint4*)&Tu[0] = *(const uint4*)&T1[pt][m][kt * 32 + quad * 8];
                *(uint4*)&Tu[4] = *(const uint4*)&T1[pt][m][kt * 32 + quad * 8 + 4];
                unpack_a(Tu, &Ah, &Al);
                acc = mfma3(acc, Ah, Al, Bh[1][kt], Bl[1][kt]);
            }
            float mx = -3.0e38f;
            #pragma unroll
            for (int r = 0; r < 4; ++r) {
                float v = acc[r] + bias2;
                v = fmaxf(v, LEAKY * v);
                mx = fmaxf(mx, v);
            }
            mx = fmaxf(mx, __shfl_xor(mx, 16));
            mx = fmaxf(mx, __shfl_xor(mx, 32));
            if (quad == 0) sm[g * 4 + pt][ocol] = mx;
        }
        __syncthreads();   // T0(g+1) ready for B(g+1); sm(g) visible
    }

    // ---- stage D: final 64->128 linear, 16 points, weights loaded once -----
    {
        const float* __restrict__ tw = dir ? t2w : t1w;
        const float* __restrict__ tb = dir ? t2b : t1b;
        const int o  = t & 127;
        const int pg = t >> 7;                 // 0..1: which pairs this thread owns
        float acc[8];
        const float bz = tb[o];
        #pragma unroll
        for (int i = 0; i < 8; ++i) acc[i] = bz;
        #pragma unroll
        for (int cc = 0; cc < 64; cc += 4) {
            const float4 wq = *(const float4*)&tw[(size_t)o * 64 + cc];
            #pragma unroll
            for (int pr = 0; pr < 4; ++pr) {
                const int pa = (2 * pr + pg) * 2;       // pair -> even point
                const float4 a0 = *(const float4*)&sm[pa][cc];
                const float4 a1 = *(const float4*)&sm[pa + 1][cc];
                float x0 = acc[2 * pr], x1 = acc[2 * pr + 1];
                x0 = fmaf(a0.x, wq.x, x0); x0 = fmaf(a0.y, wq.y, x0);
                x0 = fmaf(a0.z, wq.z, x0); x0 = fmaf(a0.w, wq.w, x0);
                x1 = fmaf(a1.x, wq.x, x1); x1 = fmaf(a1.y, wq.y, x1);
                x1 = fmaf(a1.z, wq.z, x1); x1 = fmaf(a1.w, wq.w, x1);
                acc[2 * pr] = x0; acc[2 * pr + 1] = x1;
            }
        }
        float* op = out + (size_t)dir * (2 * NPTS * 128);
        #pragma unroll
        for (int pr = 0; pr < 4; ++pr) {
            const int pa = (2 * pr + pg) * 2;
            op[((size_t)bt * NPTS + n0 + pa) * 128 + o]     = acc[2 * pr];
            op[((size_t)bt * NPTS + n0 + pa + 1) * 128 + o] = acc[2 * pr + 1];
        }
    }
}

// ---------------------------------------------------------------------------
extern "C" void kernel_launch(void* const* d_in, const int* in_sizes, int n_in,
                              void* d_out, int out_size, void* d_ws, size_t ws_size,
                              hipStream_t stream)
{
    const float* pc1   = (const float*)d_in[0];
    const float* pc2   = (const float*)d_in[1];
    const float* feat1 = (const float*)d_in[2];
    const float* feat2 = (const float*)d_in[3];
    const float* pos_w = (const float*)d_in[4];
    const float* pos_b = (const float*)d_in[5];
    const float* w0    = (const float*)d_in[6];
    const float* b0    = (const float*)d_in[7];
    const float* w1    = (const float*)d_in[8];
    const float* b1    = (const float*)d_in[9];
    const float* t1w   = (const float*)d_in[10];
    const float* t1b   = (const float*)d_in[11];
    const float* t2w   = (const float*)d_in[12];
    const float* t2b   = (const float*)d_in[13];

    int*   knn = (int*)d_ws;          // 32768 * 16 ints = 2 MB scratch
    float* out = (float*)d_out;

    hipLaunchKernelGGL(knn_kernel, dim3(32768 / QPB), dim3(KTH), 0, stream,
                       pc1, pc2, knn);
    hipLaunchKernelGGL(feat_kernel, dim3(32768 / PTS), dim3(256), 0, stream,
                       pc1, pc2, feat1, feat2, pos_w, pos_b,
                       w0, b0, w1, b1, t1w, t1b, t2w, t2b, knn, out);
}